// Round 17
// baseline (312.716 us; speedup 1.0000x reference)
//
#include <hip/hip_runtime.h>
#include <math.h>

#define NN 50000
#define NE 800000
#define HEADS 4
#define FDIM 64
#define CDIM 256   // HEADS*FDIM
#define CAP 64     // per-dst bucket capacity; P(deg>64)~0 for Poisson(16)
#define NEG_SLOPE 0.2f
#define AGG_WAVES 4    // dst nodes per aggregate block (256 threads; best measured)

typedef __attribute__((ext_vector_type(8))) _Float16 f16x8;
typedef __attribute__((ext_vector_type(2))) _Float16 f16x2;
typedef __attribute__((ext_vector_type(4))) float f32x4;
typedef __attribute__((ext_vector_type(4))) unsigned uint4v;

__device__ inline f16x2 u2h(unsigned u) {
    union { unsigned u; f16x2 h; } x; x.u = u; return x.h;
}

__device__ inline void gl_lds16(const void* g, void* l) {
    __builtin_amdgcn_global_load_lds(
        (const __attribute__((address_space(1))) void*)g,
        (__attribute__((address_space(3))) void*)l, 16, 0, 0);
}

// ---------------- bucket build: store SRC NODE ID directly ----------------
__global__ __launch_bounds__(256) void count_bucket(const int* __restrict__ src,
                                                    const int* __restrict__ dst,
                                                    int* __restrict__ deg,
                                                    int* __restrict__ bsrc) {
    int e = blockIdx.x * 256 + threadIdx.x;
    if (e >= NE) return;
    int d = dst[e];
    int c = atomicAdd(&deg[d], 1);
    if (c < CAP) bsrc[d * CAP + c] = src[e];
}

// ---------------- one-shot conversions: h -> f16, W0/1/2 -> f16 transposed ----------------
#define NH (NN * 128)
__global__ __launch_bounds__(256) void conv_all(const float* __restrict__ h,
                                                const float* __restrict__ W0,
                                                const float* __restrict__ W1,
                                                const float* __restrict__ W2,
                                                _Float16* __restrict__ xf,
                                                _Float16* __restrict__ wt0,
                                                _Float16* __restrict__ wt1,
                                                _Float16* __restrict__ wt2) {
    int i = blockIdx.x * 256 + threadIdx.x;
    if (i < NH) {
        xf[i] = (_Float16)h[i];
        return;
    }
    int j = i - NH;
    if (j < 128 * 256) {
        int k = j >> 8, n = j & 255;
        wt0[n * 128 + k] = (_Float16)W0[j];
        return;
    }
    j -= 128 * 256;
    if (j < 256 * 256) {
        int k = j >> 8, n = j & 255;
        wt1[n * 256 + k] = (_Float16)W1[j];
        return;
    }
    j -= 256 * 256;
    if (j < 256 * 256) {
        int k = j >> 8, n = j & 255;
        wt2[n * 256 + k] = (_Float16)W2[j];
    }
}
#define CONV_TOTAL (NH + 128 * 256 + 2 * 256 * 256)

// ---------------- f16 MFMA GEMM: 64x128 tile, grid-dense ----------------
// 1564 blocks (6.1/CU, 5 resident via launch_bounds) vs 782 before: the GEMM
// was grid-starved (3.05 blocks/CU), so barrier drains had nothing to overlap
// with. Wave (wr,wc) owns 32 rows x 64 cols = one head's F-range -> el/er
// epilogue unchanged. BK=64 single-buffer loop (proven). XCD-pair swizzle:
// (x,0)/(x,1) are 8 block-IDs apart -> same XCD -> A stripe L2-reused.
template<int K>
__global__ __launch_bounds__(256, 5) void gemm_f16(
    const _Float16* __restrict__ A,
    const _Float16* __restrict__ Bt,
    const float* __restrict__ alv,
    const float* __restrict__ arv,
    _Float16* __restrict__ C,
    float* __restrict__ el,
    float* __restrict__ er, int M)
{
    __shared__ __align__(16) _Float16 sA[64 * 64];    // 8 KB
    __shared__ __align__(16) _Float16 sB[128 * 64];   // 16 KB

    const int tid = threadIdx.x;
    const int lane = tid & 63, w = tid >> 6;

    // swizzle: groups of 16 ids = 8 x-values x 2 y; pair (x,0)/(x,1) 8 apart
    int bid = blockIdx.x;
    int gx, gy;
    if (bid < 1552) { gx = ((bid >> 4) << 3) | (bid & 7); gy = (bid >> 3) & 1; }
    else            { int tb = bid - 1552; gx = 776 + (tb % 6); gy = tb / 6; }

    const int m0 = gx * 64, n0 = gy * 128;
    const int wr = w >> 1, wc = w & 1;      // wave: 32 rows x 64 cols (one head)
    const int ln15 = lane & 15, lhi = lane >> 4;

    f32x4 acc[2][4] = {};

    for (int k0 = 0; k0 < K; k0 += 64) {
        // stage 24 x 1KB chunks: A (8) then B (16); 6 per wave, wave-uniform ids
        #pragma unroll
        for (int it = 0; it < 6; ++it) {
            int g = w * 6 + it;
            int rsub = lane >> 3;
            int col = (lane & 7) * 8;
            if (g < 8) {
                int ar = m0 + g * 8 + rsub; ar = ar < M ? ar : M - 1;
                gl_lds16(A + (size_t)ar * K + k0 + col, sA + g * 512);
            } else {
                int c = g - 8;
                gl_lds16(Bt + (size_t)(n0 + c * 8 + rsub) * K + k0 + col, sB + c * 512);
            }
        }
        __syncthreads();
        const f16x8* A8 = (const f16x8*)sA;
        const f16x8* B8 = (const f16x8*)sB;
        #pragma unroll
        for (int kk = 0; kk < 2; ++kk) {
            f16x8 a[2], b[4];
            #pragma unroll
            for (int i = 0; i < 2; ++i) {
                int ri = wr * 32 + i * 16 + ln15;
                a[i] = A8[ri * 8 + kk * 4 + lhi];
            }
            #pragma unroll
            for (int j = 0; j < 4; ++j) {
                int ci = wc * 64 + j * 16 + ln15;
                b[j] = B8[ci * 8 + kk * 4 + lhi];
            }
            #pragma unroll
            for (int i = 0; i < 2; ++i) {
                #pragma unroll
                for (int j = 0; j < 4; ++j) {
                    acc[i][j] = __builtin_amdgcn_mfma_f32_16x16x32_f16(a[i], b[j], acc[i][j], 0, 0, 0);
                }
            }
        }
        __syncthreads();
    }

    const int head = gy * 2 + wc;
    float alW[4], arW[4];
    #pragma unroll
    for (int j = 0; j < 4; ++j) {
        alW[j] = alv[head * FDIM + j * 16 + ln15];
        arW[j] = arv[head * FDIM + j * 16 + ln15];
    }

    #pragma unroll
    for (int i = 0; i < 2; ++i) {
        #pragma unroll
        for (int r = 0; r < 4; ++r) {
            int row = m0 + wr * 32 + i * 16 + lhi * 4 + r;
            float pl = 0.f, pr = 0.f;
            #pragma unroll
            for (int j = 0; j < 4; ++j) {
                float cv = acc[i][j][r];
                pl += cv * alW[j];
                pr += cv * arW[j];
                if (row < M) C[(size_t)row * CDIM + n0 + wc * 64 + j * 16 + ln15] = (_Float16)cv;
            }
            #pragma unroll
            for (int o = 1; o < 16; o <<= 1) {
                pl += __shfl_xor(pl, o, 64);
                pr += __shfl_xor(pr, o, 64);
            }
            if (ln15 == 0 && row < M) {
                el[row * HEADS + head] = pl;
                er[row * HEADS + head] = pr;
            }
        }
    }
}

// ---------------- aggregation: 4 dst-waves per 256-thread block (round-14 form) ----------------
// Per wave: phase A (sn + el-row -> LDS), phase B (wave-parallel softmax, alpha
// f16 -> LDS), phase C (edge-pair dot2 gather, uint4 row loads, unroll 4).
template<int MODE>
__global__ __launch_bounds__(256) void aggregate(const int* __restrict__ deg,
                                                 const int* __restrict__ bsrc,
                                                 const float* __restrict__ el,
                                                 const float* __restrict__ er,
                                                 const _Float16* __restrict__ feat16,
                                                 _Float16* __restrict__ xf,
                                                 float* __restrict__ outp) {
    __shared__ int      sn[AGG_WAVES][CAP + 1];
    __shared__ f32x4    s_el[AGG_WAVES][CAP];
    __shared__ _Float16 a_f16[AGG_WAVES][HEADS * (CAP + 2)];   // [head][edge], +pad
    const int t = threadIdx.x;
    const int wv = t >> 6, l = t & 63;
    const int d = blockIdx.x * AGG_WAVES + wv;   // NN divisible by AGG_WAVES
    const int dg = min(deg[d], CAP);

    // A: edge src ids + their el rows -> LDS; boundary entries zeroed
    if (l < dg) {
        int s = bsrc[d * CAP + l];
        sn[wv][l] = s;
        s_el[wv][l] = *(const f32x4*)(el + (size_t)s * HEADS);
    }
    if (l == dg) sn[wv][l] = 0;
    if (l < HEADS) a_f16[wv][l * (CAP + 2) + dg] = (_Float16)0.f;
    __syncthreads();

    // B: logits + wave-parallel softmax. lane = h4 + 4*c4. Pure LDS reads.
    const int c4 = l >> 2, h4 = l & 3;
    const float erh = er[d * HEADS + h4];
    const int kn = (dg + 15) >> 4;              // active 16-edge groups (uniform)
    float vv[CAP / 16];
    float m = -INFINITY;
    #pragma unroll
    for (int k = 0; k < CAP / 16; ++k) {
        if (k < kn) {
            int ce = c4 + 16 * k;
            float x = -INFINITY;
            if (ce < dg) {
                x = s_el[wv][ce][h4] + erh;
                x = x > 0.f ? x : NEG_SLOPE * x;
            }
            vv[k] = x;
            m = fmaxf(m, x);
        }
    }
    #pragma unroll
    for (int o = 4; o < 64; o <<= 1) m = fmaxf(m, __shfl_xor(m, o, 64));
    float s = 0.f;
    #pragma unroll
    for (int k = 0; k < CAP / 16; ++k) {
        if (k < kn) s += __expf(vv[k] - m);     // exp(-inf) = 0
    }
    #pragma unroll
    for (int o = 4; o < 64; o <<= 1) s += __shfl_xor(s, o, 64);
    float rs = dg > 0 ? 1.f / s : 0.f;
    #pragma unroll
    for (int k = 0; k < CAP / 16; ++k) {
        if (k < kn) {
            int ce = c4 + 16 * k;
            if (ce < dg) a_f16[wv][h4 * (CAP + 2) + ce] = (_Float16)(__expf(vv[k] - m) * rs);
        }
    }
    __syncthreads();

    // C: gather edge PAIRS. u = pair parity, q = column octet (8 f16 = 16B)
    const int u = l >> 5, q = l & 31;
    const int hh = q >> 3;
    float acc[8] = {};
    #pragma unroll 4
    for (int c0 = 2 * u; c0 < dg; c0 += 4) {
        unsigned ap = *(const unsigned*)&a_f16[wv][hh * (CAP + 2) + c0];  // (a0,a1)
        int s0 = sn[wv][c0], s1 = sn[wv][c0 + 1];
        uint4v D0 = *(const uint4v*)(feat16 + (size_t)s0 * CDIM + q * 8);
        uint4v D1 = *(const uint4v*)(feat16 + (size_t)s1 * CDIM + q * 8);
        f16x2 a2 = u2h(ap);
        #pragma unroll
        for (int j = 0; j < 4; ++j) {
#if __has_builtin(__builtin_amdgcn_fdot2)
            unsigned plo = __builtin_amdgcn_perm(D1[j], D0[j], 0x05040100u); // (f0_lo, f1_lo)
            unsigned phi = __builtin_amdgcn_perm(D1[j], D0[j], 0x07060302u); // (f0_hi, f1_hi)
            acc[2 * j]     = __builtin_amdgcn_fdot2(u2h(plo), a2, acc[2 * j], false);
            acc[2 * j + 1] = __builtin_amdgcn_fdot2(u2h(phi), a2, acc[2 * j + 1], false);
#else
            f16x2 e0 = u2h(D0[j]), e1 = u2h(D1[j]);
            float a0 = (float)a2[0], a1 = (float)a2[1];
            acc[2 * j]     += a0 * (float)e0[0] + a1 * (float)e1[0];
            acc[2 * j + 1] += a0 * (float)e0[1] + a1 * (float)e1[1];
#endif
        }
    }
    #pragma unroll
    for (int j = 0; j < 8; ++j) acc[j] += __shfl_xor(acc[j], 32, 64);

    if (MODE == 0) {
        if (u == 0) {
            f16x8 vh;
            #pragma unroll
            for (int j = 0; j < 8; ++j) {
                float x = acc[j];
                x = x > 0.f ? x : (__expf(x) - 1.f);   // ELU via v_exp_f32
                vh[j] = (_Float16)x;
            }
            *(f16x8*)(xf + (size_t)d * CDIM + q * 8) = vh;
        }
    } else {
        // head-mean: combine lanes q, q^8, q^16 (same within-head offset)
        #pragma unroll
        for (int j = 0; j < 8; ++j) {
            acc[j] += __shfl_xor(acc[j], 8, 64);
            acc[j] += __shfl_xor(acc[j], 16, 64);
        }
        if (u == 0 && q < 8) {
            f32x4 o0, o1;
            #pragma unroll
            for (int j = 0; j < 4; ++j) { o0[j] = acc[j] * 0.25f; o1[j] = acc[4 + j] * 0.25f; }
            *(f32x4*)(outp + (size_t)d * FDIM + q * 8) = o0;
            *(f32x4*)(outp + (size_t)d * FDIM + q * 8 + 4) = o1;
        }
    }
}

extern "C" void kernel_launch(void* const* d_in, const int* in_sizes, int n_in,
                              void* d_out, int out_size, void* d_ws, size_t ws_size,
                              hipStream_t stream) {
    const float* h   = (const float*)d_in[0];
    const float* W0  = (const float*)d_in[1];
    const float* al0 = (const float*)d_in[2];
    const float* ar0 = (const float*)d_in[3];
    const float* W1  = (const float*)d_in[4];
    const float* al1 = (const float*)d_in[5];
    const float* ar1 = (const float*)d_in[6];
    const float* W2  = (const float*)d_in[7];
    const float* al2 = (const float*)d_in[8];
    const float* ar2 = (const float*)d_in[9];
    const int* src = (const int*)d_in[10];
    const int* dst = (const int*)d_in[11];
    float* out = (float*)d_out;

    char* ws = (char*)d_ws;
    size_t off = 0;
    auto alloc = [&](size_t bytes) {
        void* p = ws + off;
        off += (bytes + 255) & ~(size_t)255;
        return p;
    };
    _Float16* feat16 = (_Float16*)alloc((size_t)NN * CDIM * 2);
    _Float16* xf     = (_Float16*)alloc((size_t)NN * CDIM * 2);
    _Float16* wt0    = (_Float16*)alloc((size_t)256 * 128 * 2);
    _Float16* wt1    = (_Float16*)alloc((size_t)256 * 256 * 2);
    _Float16* wt2    = (_Float16*)alloc((size_t)256 * 256 * 2);
    float* el     = (float*)alloc((size_t)NN * HEADS * 4);
    float* er     = (float*)alloc((size_t)NN * HEADS * 4);
    int*   deg    = (int*)alloc((size_t)NN * 4);
    int*   bsrc   = (int*)alloc((size_t)NN * CAP * 4);

    // conversions first (independent of graph build)
    conv_all<<<(CONV_TOTAL + 255) / 256, 256, 0, stream>>>(h, W0, W1, W2, xf, wt0, wt1, wt2);

    hipMemsetAsync(deg, 0, NN * 4, stream);
    count_bucket<<<NE / 256, 256, 0, stream>>>(src, dst, deg, bsrc);

    const int gemmBlocks = 1564;                // 782 x-tiles x 2 y-halves, 1D swizzled
    const int aggBlocks = NN / AGG_WAVES;       // 12500

    // ---- layer 0 ----
    gemm_f16<128><<<gemmBlocks, 256, 0, stream>>>(xf, wt0, al0, ar0, feat16, el, er, NN);
    aggregate<0><<<aggBlocks, 256, 0, stream>>>(deg, bsrc, el, er, feat16, xf, nullptr);

    // ---- layer 1 ----
    gemm_f16<256><<<gemmBlocks, 256, 0, stream>>>(xf, wt1, al1, ar1, feat16, el, er, NN);
    aggregate<0><<<aggBlocks, 256, 0, stream>>>(deg, bsrc, el, er, feat16, xf, nullptr);

    // ---- layer 2 (output: mean over heads) ----
    gemm_f16<256><<<gemmBlocks, 256, 0, stream>>>(xf, wt2, al2, ar2, feat16, el, er, NN);
    aggregate<1><<<aggBlocks, 256, 0, stream>>>(deg, bsrc, el, er, feat16, nullptr, out);
}

// Round 18
// 307.869 us; speedup vs baseline: 1.0157x; 1.0157x over previous
//
#include <hip/hip_runtime.h>
#include <math.h>

#define NN 50000
#define NE 800000
#define HEADS 4
#define FDIM 64
#define CDIM 256   // HEADS*FDIM
#define CAP 64     // per-dst bucket capacity; P(deg>64)~0 for Poisson(16)
#define NEG_SLOPE 0.2f
#define AGG_WAVES 4    // dst nodes per aggregate block (256 threads; best measured)

typedef __attribute__((ext_vector_type(8))) _Float16 f16x8;
typedef __attribute__((ext_vector_type(2))) _Float16 f16x2;
typedef __attribute__((ext_vector_type(4))) float f32x4;
typedef __attribute__((ext_vector_type(4))) unsigned uint4v;

__device__ inline f16x2 u2h(unsigned u) {
    union { unsigned u; f16x2 h; } x; x.u = u; return x.h;
}

__device__ inline void gl_lds16(const void* g, void* l) {
    __builtin_amdgcn_global_load_lds(
        (const __attribute__((address_space(1))) void*)g,
        (__attribute__((address_space(3))) void*)l, 16, 0, 0);
}

// ---------------- bucket build: store SRC NODE ID directly ----------------
__global__ __launch_bounds__(256) void count_bucket(const int* __restrict__ src,
                                                    const int* __restrict__ dst,
                                                    int* __restrict__ deg,
                                                    int* __restrict__ bsrc) {
    int e = blockIdx.x * 256 + threadIdx.x;
    if (e >= NE) return;
    int d = dst[e];
    int c = atomicAdd(&deg[d], 1);
    if (c < CAP) bsrc[d * CAP + c] = src[e];
}

// ---------------- one-shot conversions: h -> f16, W0/1/2 -> f16 transposed ----------------
#define NH (NN * 128)
__global__ __launch_bounds__(256) void conv_all(const float* __restrict__ h,
                                                const float* __restrict__ W0,
                                                const float* __restrict__ W1,
                                                const float* __restrict__ W2,
                                                _Float16* __restrict__ xf,
                                                _Float16* __restrict__ wt0,
                                                _Float16* __restrict__ wt1,
                                                _Float16* __restrict__ wt2) {
    int i = blockIdx.x * 256 + threadIdx.x;
    if (i < NH) {
        xf[i] = (_Float16)h[i];
        return;
    }
    int j = i - NH;
    if (j < 128 * 256) {
        int k = j >> 8, n = j & 255;
        wt0[n * 128 + k] = (_Float16)W0[j];
        return;
    }
    j -= 128 * 256;
    if (j < 256 * 256) {
        int k = j >> 8, n = j & 255;
        wt1[n * 256 + k] = (_Float16)W1[j];
        return;
    }
    j -= 256 * 256;
    if (j < 256 * 256) {
        int k = j >> 8, n = j & 255;
        wt2[n * 256 + k] = (_Float16)W2[j];
    }
}
#define CONV_TOTAL (NH + 128 * 256 + 2 * 256 * 256)

// ---------------- f16 MFMA GEMM + fused el/er epilogue (round-14 best form) ----------------
// 128x128 tile, BK=64 single-buffer, 4 blocks/CU. 1D grid, XCD-pair swizzle:
// (x,0)/(x,1) are 8 block-IDs apart -> same XCD -> shared A stripe L2-reused.
template<int K>
__global__ __launch_bounds__(256, 4) void gemm_f16(
    const _Float16* __restrict__ A,
    const _Float16* __restrict__ Bt,
    const float* __restrict__ alv,
    const float* __restrict__ arv,
    _Float16* __restrict__ C,
    float* __restrict__ el,
    float* __restrict__ er, int M)
{
    __shared__ __align__(16) _Float16 sA[128 * 64];   // 16 KB
    __shared__ __align__(16) _Float16 sB[128 * 64];   // 16 KB

    const int tid = threadIdx.x;
    const int lane = tid & 63, w = tid >> 6;

    // swizzle: groups of 16 ids = 8 x-values x 2 y; pair (x,0)/(x,1) 8 apart
    int bid = blockIdx.x;
    int gx, gy;
    if (bid < 768) { gx = ((bid >> 4) << 3) | (bid & 7); gy = (bid >> 3) & 1; }
    else           { int tb = bid - 768; gx = 384 + (tb % 7); gy = tb / 7; }

    const int m0 = gx * 128, n0 = gy * 128;
    const int wr = w >> 1, wc = w & 1;      // 2x2 waves, each owns 64x64 out
    const int ln15 = lane & 15, lhi = lane >> 4;

    f32x4 acc[4][4] = {};

    for (int k0 = 0; k0 < K; k0 += 64) {
        #pragma unroll
        for (int it = 0; it < 4; ++it) {
            int c = w * 4 + it;               // 1KB chunk id, wave-uniform
            int r = c * 8 + (lane >> 3);      // tile row this lane sources
            int col = (lane & 7) * 8;         // f16 col offset (16B)
            int ar = m0 + r; ar = ar < M ? ar : M - 1;
            gl_lds16(A + (size_t)ar * K + k0 + col, sA + c * 512);
            gl_lds16(Bt + (size_t)(n0 + r) * K + k0 + col, sB + c * 512);
        }
        __syncthreads();
        const f16x8* A8 = (const f16x8*)sA;
        const f16x8* B8 = (const f16x8*)sB;
        #pragma unroll
        for (int kk = 0; kk < 2; ++kk) {
            f16x8 a[4], b[4];
            #pragma unroll
            for (int i = 0; i < 4; ++i) {
                int ri = wr * 64 + i * 16 + ln15;
                a[i] = A8[ri * 8 + kk * 4 + lhi];
                int ci = wc * 64 + i * 16 + ln15;
                b[i] = B8[ci * 8 + kk * 4 + lhi];
            }
            #pragma unroll
            for (int i = 0; i < 4; ++i) {
                #pragma unroll
                for (int j = 0; j < 4; ++j) {
                    acc[i][j] = __builtin_amdgcn_mfma_f32_16x16x32_f16(a[i], b[j], acc[i][j], 0, 0, 0);
                }
            }
        }
        __syncthreads();
    }

    const int head = gy * 2 + wc;
    float alW[4], arW[4];
    #pragma unroll
    for (int j = 0; j < 4; ++j) {
        alW[j] = alv[head * FDIM + j * 16 + ln15];
        arW[j] = arv[head * FDIM + j * 16 + ln15];
    }

    #pragma unroll
    for (int i = 0; i < 4; ++i) {
        #pragma unroll
        for (int r = 0; r < 4; ++r) {
            int row = m0 + wr * 64 + i * 16 + lhi * 4 + r;
            float pl = 0.f, pr = 0.f;
            #pragma unroll
            for (int j = 0; j < 4; ++j) {
                float cv = acc[i][j][r];
                pl += cv * alW[j];
                pr += cv * arW[j];
                if (row < M) C[(size_t)row * CDIM + n0 + wc * 64 + j * 16 + ln15] = (_Float16)cv;
            }
            #pragma unroll
            for (int o = 1; o < 16; o <<= 1) {
                pl += __shfl_xor(pl, o, 64);
                pr += __shfl_xor(pr, o, 64);
            }
            if (ln15 == 0 && row < M) {
                el[row * HEADS + head] = pl;
                er[row * HEADS + head] = pr;
            }
        }
    }
}

// ---------------- aggregation: 4 dst-waves per 256-thread block (round-14 form) ----------------
// Per wave: phase A (sn + el-row -> LDS), phase B (wave-parallel softmax, alpha
// f16 -> LDS), phase C (edge-pair dot2 gather, uint4 row loads, unroll 4).
template<int MODE>
__global__ __launch_bounds__(256) void aggregate(const int* __restrict__ deg,
                                                 const int* __restrict__ bsrc,
                                                 const float* __restrict__ el,
                                                 const float* __restrict__ er,
                                                 const _Float16* __restrict__ feat16,
                                                 _Float16* __restrict__ xf,
                                                 float* __restrict__ outp) {
    __shared__ int      sn[AGG_WAVES][CAP + 1];
    __shared__ f32x4    s_el[AGG_WAVES][CAP];
    __shared__ _Float16 a_f16[AGG_WAVES][HEADS * (CAP + 2)];   // [head][edge], +pad
    const int t = threadIdx.x;
    const int wv = t >> 6, l = t & 63;
    const int d = blockIdx.x * AGG_WAVES + wv;   // NN divisible by AGG_WAVES
    const int dg = min(deg[d], CAP);

    // A: edge src ids + their el rows -> LDS; boundary entries zeroed
    if (l < dg) {
        int s = bsrc[d * CAP + l];
        sn[wv][l] = s;
        s_el[wv][l] = *(const f32x4*)(el + (size_t)s * HEADS);
    }
    if (l == dg) sn[wv][l] = 0;
    if (l < HEADS) a_f16[wv][l * (CAP + 2) + dg] = (_Float16)0.f;
    __syncthreads();

    // B: logits + wave-parallel softmax. lane = h4 + 4*c4. Pure LDS reads.
    const int c4 = l >> 2, h4 = l & 3;
    const float erh = er[d * HEADS + h4];
    const int kn = (dg + 15) >> 4;              // active 16-edge groups (uniform)
    float vv[CAP / 16];
    float m = -INFINITY;
    #pragma unroll
    for (int k = 0; k < CAP / 16; ++k) {
        if (k < kn) {
            int ce = c4 + 16 * k;
            float x = -INFINITY;
            if (ce < dg) {
                x = s_el[wv][ce][h4] + erh;
                x = x > 0.f ? x : NEG_SLOPE * x;
            }
            vv[k] = x;
            m = fmaxf(m, x);
        }
    }
    #pragma unroll
    for (int o = 4; o < 64; o <<= 1) m = fmaxf(m, __shfl_xor(m, o, 64));
    float s = 0.f;
    #pragma unroll
    for (int k = 0; k < CAP / 16; ++k) {
        if (k < kn) s += __expf(vv[k] - m);     // exp(-inf) = 0
    }
    #pragma unroll
    for (int o = 4; o < 64; o <<= 1) s += __shfl_xor(s, o, 64);
    float rs = dg > 0 ? 1.f / s : 0.f;
    #pragma unroll
    for (int k = 0; k < CAP / 16; ++k) {
        if (k < kn) {
            int ce = c4 + 16 * k;
            if (ce < dg) a_f16[wv][h4 * (CAP + 2) + ce] = (_Float16)(__expf(vv[k] - m) * rs);
        }
    }
    __syncthreads();

    // C: gather edge PAIRS. u = pair parity, q = column octet (8 f16 = 16B)
    const int u = l >> 5, q = l & 31;
    const int hh = q >> 3;
    float acc[8] = {};
    #pragma unroll 4
    for (int c0 = 2 * u; c0 < dg; c0 += 4) {
        unsigned ap = *(const unsigned*)&a_f16[wv][hh * (CAP + 2) + c0];  // (a0,a1)
        int s0 = sn[wv][c0], s1 = sn[wv][c0 + 1];
        uint4v D0 = *(const uint4v*)(feat16 + (size_t)s0 * CDIM + q * 8);
        uint4v D1 = *(const uint4v*)(feat16 + (size_t)s1 * CDIM + q * 8);
        f16x2 a2 = u2h(ap);
        #pragma unroll
        for (int j = 0; j < 4; ++j) {
#if __has_builtin(__builtin_amdgcn_fdot2)
            unsigned plo = __builtin_amdgcn_perm(D1[j], D0[j], 0x05040100u); // (f0_lo, f1_lo)
            unsigned phi = __builtin_amdgcn_perm(D1[j], D0[j], 0x07060302u); // (f0_hi, f1_hi)
            acc[2 * j]     = __builtin_amdgcn_fdot2(u2h(plo), a2, acc[2 * j], false);
            acc[2 * j + 1] = __builtin_amdgcn_fdot2(u2h(phi), a2, acc[2 * j + 1], false);
#else
            f16x2 e0 = u2h(D0[j]), e1 = u2h(D1[j]);
            float a0 = (float)a2[0], a1 = (float)a2[1];
            acc[2 * j]     += a0 * (float)e0[0] + a1 * (float)e1[0];
            acc[2 * j + 1] += a0 * (float)e0[1] + a1 * (float)e1[1];
#endif
        }
    }
    #pragma unroll
    for (int j = 0; j < 8; ++j) acc[j] += __shfl_xor(acc[j], 32, 64);

    if (MODE == 0) {
        if (u == 0) {
            f16x8 vh;
            #pragma unroll
            for (int j = 0; j < 8; ++j) {
                float x = acc[j];
                x = x > 0.f ? x : (__expf(x) - 1.f);   // ELU via v_exp_f32
                vh[j] = (_Float16)x;
            }
            *(f16x8*)(xf + (size_t)d * CDIM + q * 8) = vh;
        }
    } else {
        // head-mean: combine lanes q, q^8, q^16 (same within-head offset)
        #pragma unroll
        for (int j = 0; j < 8; ++j) {
            acc[j] += __shfl_xor(acc[j], 8, 64);
            acc[j] += __shfl_xor(acc[j], 16, 64);
        }
        if (u == 0 && q < 8) {
            f32x4 o0, o1;
            #pragma unroll
            for (int j = 0; j < 4; ++j) { o0[j] = acc[j] * 0.25f; o1[j] = acc[4 + j] * 0.25f; }
            *(f32x4*)(outp + (size_t)d * FDIM + q * 8) = o0;
            *(f32x4*)(outp + (size_t)d * FDIM + q * 8 + 4) = o1;
        }
    }
}

extern "C" void kernel_launch(void* const* d_in, const int* in_sizes, int n_in,
                              void* d_out, int out_size, void* d_ws, size_t ws_size,
                              hipStream_t stream) {
    const float* h   = (const float*)d_in[0];
    const float* W0  = (const float*)d_in[1];
    const float* al0 = (const float*)d_in[2];
    const float* ar0 = (const float*)d_in[3];
    const float* W1  = (const float*)d_in[4];
    const float* al1 = (const float*)d_in[5];
    const float* ar1 = (const float*)d_in[6];
    const float* W2  = (const float*)d_in[7];
    const float* al2 = (const float*)d_in[8];
    const float* ar2 = (const float*)d_in[9];
    const int* src = (const int*)d_in[10];
    const int* dst = (const int*)d_in[11];
    float* out = (float*)d_out;

    char* ws = (char*)d_ws;
    size_t off = 0;
    auto alloc = [&](size_t bytes) {
        void* p = ws + off;
        off += (bytes + 255) & ~(size_t)255;
        return p;
    };
    _Float16* feat16 = (_Float16*)alloc((size_t)NN * CDIM * 2);
    _Float16* xf     = (_Float16*)alloc((size_t)NN * CDIM * 2);
    _Float16* wt0    = (_Float16*)alloc((size_t)256 * 128 * 2);
    _Float16* wt1    = (_Float16*)alloc((size_t)256 * 256 * 2);
    _Float16* wt2    = (_Float16*)alloc((size_t)256 * 256 * 2);
    float* el     = (float*)alloc((size_t)NN * HEADS * 4);
    float* er     = (float*)alloc((size_t)NN * HEADS * 4);
    int*   deg    = (int*)alloc((size_t)NN * 4);
    int*   bsrc   = (int*)alloc((size_t)NN * CAP * 4);

    // conversions first (independent of graph build)
    conv_all<<<(CONV_TOTAL + 255) / 256, 256, 0, stream>>>(h, W0, W1, W2, xf, wt0, wt1, wt2);

    hipMemsetAsync(deg, 0, NN * 4, stream);
    count_bucket<<<NE / 256, 256, 0, stream>>>(src, dst, deg, bsrc);

    const int gemmBlocks = 782;                 // 391 x-tiles x 2 y-halves, 1D swizzled
    const int aggBlocks = NN / AGG_WAVES;       // 12500

    // ---- layer 0 ----
    gemm_f16<128><<<gemmBlocks, 256, 0, stream>>>(xf, wt0, al0, ar0, feat16, el, er, NN);
    aggregate<0><<<aggBlocks, 256, 0, stream>>>(deg, bsrc, el, er, feat16, xf, nullptr);

    // ---- layer 1 ----
    gemm_f16<256><<<gemmBlocks, 256, 0, stream>>>(xf, wt1, al1, ar1, feat16, el, er, NN);
    aggregate<0><<<aggBlocks, 256, 0, stream>>>(deg, bsrc, el, er, feat16, xf, nullptr);

    // ---- layer 2 (output: mean over heads) ----
    gemm_f16<256><<<gemmBlocks, 256, 0, stream>>>(xf, wt2, al2, ar2, feat16, el, er, NN);
    aggregate<1><<<aggBlocks, 256, 0, stream>>>(deg, bsrc, el, er, feat16, nullptr, out);
}